// Round 1
// baseline (243.915 us; speedup 1.0000x reference)
//
#include <hip/hip_runtime.h>

#define SM_N 4096
#define HID 96

// One thread = one 4x4 tile. Workgroup = 256 threads = 4 tile-rows of one
// 256x256 block chunk (wave = one tile-row, lane = tile-col -> coalesced
// float4 loads/stores). All weight/bias accesses are workgroup-uniform ->
// scalar loads (s_load) feeding v_fmac with SGPR operand.
__global__ __launch_bounds__(256) void adapter_kernel(
    const float* __restrict__ sm,
    const float* __restrict__ w1,    // [256][16][96]
    const float* __restrict__ b1,    // [256][96]
    const float* __restrict__ emb_h, // [256][64][8]
    const float* __restrict__ emb_w, // [256][64][8]
    const float* __restrict__ w2,    // [256][96][16]
    const float* __restrict__ b2,    // [256][16]
    const float* __restrict__ scales,// [256][16]
    float* __restrict__ out)
{
    const int wg  = blockIdx.x;      // 0..4095
    const int b   = wg >> 4;         // block 0..255
    const int ch  = wg & 15;         // chunk of 4 tile-rows
    const int obi = b >> 4, ibi = b & 15;
    const int tid = threadIdx.x;
    const int th  = (ch << 2) + (tid >> 6);  // tile row 0..63
    const int tw  = tid & 63;                // tile col 0..63

    const int row0 = obi * 256 + th * 4;
    const int col0 = ibi * 256 + tw * 4;
    const float* __restrict__ srcp = sm  + (size_t)row0 * SM_N + col0;
    float*       __restrict__ dstp = out + (size_t)row0 * SM_N + col0;

    // load the 4x4 tile (r-major), coalesced float4 per row
    float x[16];
#pragma unroll
    for (int r = 0; r < 4; ++r) {
        const float4 v = *reinterpret_cast<const float4*>(srcp + (size_t)r * SM_N);
        x[4*r+0] = v.x; x[4*r+1] = v.y; x[4*r+2] = v.z; x[4*r+3] = v.w;
    }

    // positional embeddings: h<8 -> emb_h[b][th][h], 8<=h<16 -> emb_w[b][tw][h-8]
    float vemb[16];
    {
        const float4* ph = reinterpret_cast<const float4*>(emb_h + ((size_t)b * 64 + th) * 8);
        const float4* pw = reinterpret_cast<const float4*>(emb_w + ((size_t)b * 64 + tw) * 8);
        const float4 a0 = ph[0], a1 = ph[1], c0 = pw[0], c1 = pw[1];
        vemb[0]=a0.x;  vemb[1]=a0.y;  vemb[2]=a0.z;  vemb[3]=a0.w;
        vemb[4]=a1.x;  vemb[5]=a1.y;  vemb[6]=a1.z;  vemb[7]=a1.w;
        vemb[8]=c0.x;  vemb[9]=c0.y;  vemb[10]=c0.z; vemb[11]=c0.w;
        vemb[12]=c1.x; vemb[13]=c1.y; vemb[14]=c1.z; vemb[15]=c1.w;
    }

    const float* __restrict__ w1b = w1 + (size_t)b * 16 * HID;  // [k][h]
    const float* __restrict__ w2b = w2 + (size_t)b * HID * 16;  // [h][j]
    const float* __restrict__ b1b = b1 + (size_t)b * HID;
    const float* __restrict__ b2b = b2 + (size_t)b * 16;
    const float* __restrict__ scb = scales + (size_t)b * 16;

    // out init: bias2 + scaled residual
    float o[16];
#pragma unroll
    for (int j = 0; j < 16; ++j) o[j] = b2b[j] + x[j] * scb[j];

    // h in [0,16): has positional embedding; fully unrolled so vemb[h] is
    // compile-time indexed (stays in registers).
#pragma unroll
    for (int h = 0; h < 16; ++h) {
        float acc = b1b[h] + vemb[h];
#pragma unroll
        for (int k = 0; k < 16; ++k) acc = fmaf(x[k], w1b[k*HID + h], acc);
        const float hv = acc > 0.0f ? acc : (__expf(acc) - 1.0f);  // ELU
#pragma unroll
        for (int j = 0; j < 16; ++j) o[j] = fmaf(hv, w2b[h*16 + j], o[j]);
    }
    // h in [16,96)
#pragma unroll 4
    for (int h = 16; h < HID; ++h) {
        float acc = b1b[h];
#pragma unroll
        for (int k = 0; k < 16; ++k) acc = fmaf(x[k], w1b[k*HID + h], acc);
        const float hv = acc > 0.0f ? acc : (__expf(acc) - 1.0f);
#pragma unroll
        for (int j = 0; j < 16; ++j) o[j] = fmaf(hv, w2b[h*16 + j], o[j]);
    }

    // store, coalesced float4 per row
#pragma unroll
    for (int r = 0; r < 4; ++r) {
        float4 v; v.x = o[4*r+0]; v.y = o[4*r+1]; v.z = o[4*r+2]; v.w = o[4*r+3];
        *reinterpret_cast<float4*>(dstp + (size_t)r * SM_N) = v;
    }
}

extern "C" void kernel_launch(void* const* d_in, const int* in_sizes, int n_in,
                              void* d_out, int out_size, void* d_ws, size_t ws_size,
                              hipStream_t stream) {
    const float* sm     = (const float*)d_in[0];
    const float* w1     = (const float*)d_in[1];
    const float* b1     = (const float*)d_in[2];
    const float* emb_h  = (const float*)d_in[3];
    const float* emb_w  = (const float*)d_in[4];
    const float* w2     = (const float*)d_in[5];
    const float* b2     = (const float*)d_in[6];
    const float* scales = (const float*)d_in[7];
    float* out = (float*)d_out;

    adapter_kernel<<<dim3(4096), dim3(256), 0, stream>>>(
        sm, w1, b1, emb_h, emb_w, w2, b2, scales, out);
}

// Round 2
// 147.623 us; speedup vs baseline: 1.6523x; 1.6523x over previous
//
#include <hip/hip_runtime.h>

#define SM_N 4096

typedef __attribute__((ext_vector_type(8))) short bf16x8;  // 8 bf16 = 4 VGPRs
typedef __attribute__((ext_vector_type(4))) float f32x4;

// RTNE float -> bf16 (finite inputs)
static __device__ __forceinline__ short f2bf(float f) {
    union { float f; unsigned u; } v; v.f = f;
    return (short)((v.u + 0x7fffu + ((v.u >> 16) & 1u)) >> 16);
}

static __device__ __forceinline__ float elu(float x) {
    return x > 0.0f ? x : (__expf(x) - 1.0f);
}

// Swapped-operand MFMA formulation:
//   GEMM1: D1[h][t] = sum_k W1^T[h][k] * X^T[k][t]   (K=16, zero-padded to 32)
//   GEMM2: D2[j][t] = sum_h W2^T[j][h] * H^T[h][t]   (K=96 = 3 x 32)
// Lane l (g = l>>4, ln = l&15):
//   - owns tile t = t0 + ln; its GEMM1 B-slots (g, i<4) are tile sub-row g,
//     cols 0..3 = one contiguous float4 from sm.
//   - D1 reg r holds h = hgrp*16 + 4g + r  (verified C/D layout) -> bias/emb
//     are per-lane float4 loads; ELU+bf16-pack produces GEMM2's B operand
//     directly (slot-consistent with how A2 is loaded).
//   - D2 reg r holds j = 4g + r = tile sub-row g, col r -> residual reuses the
//     fp32 float4 of X already in registers; store mirrors the load.
__global__ __launch_bounds__(256) void adapter_mfma(
    const float* __restrict__ sm,
    const float* __restrict__ w1,    // [256][16][96]
    const float* __restrict__ b1,    // [256][96]
    const float* __restrict__ emb_h, // [256][64][8]
    const float* __restrict__ emb_w, // [256][64][8]
    const float* __restrict__ w2,    // [256][96][16]
    const float* __restrict__ b2,    // [256][16]
    const float* __restrict__ scales,// [256][16]
    float* __restrict__ out)
{
    const int wg   = blockIdx.x;          // 0..4095 (16 workgroups per block)
    const int b    = wg >> 4;             // block 0..255
    const int obi  = b >> 4, ibi = b & 15;
    const int tid  = threadIdx.x;
    const int wave = tid >> 6;
    const int lane = tid & 63;
    const int g    = lane >> 4;           // 0..3: k-subrow / D row-group
    const int ln   = lane & 15;           // tile-in-group / h-in-group / j

    const int th = (wg & 15) * 4 + wave;  // tile row 0..63, fixed per wave

    const float* __restrict__ w1b = w1 + (size_t)b * 16 * 96;
    const float* __restrict__ w2b = w2 + (size_t)b * 96 * 16;
    const float* __restrict__ b1b = b1 + (size_t)b * 96;
    const float* __restrict__ b2b = b2 + (size_t)b * 16;
    const float* __restrict__ scb = scales + (size_t)b * 16;

    // ---- loop-invariant per-lane weight fragments ----
    // A1[hgrp]: W1^T, row h = hgrp*16 + ln, slot (g,i<4) = k = 4g+i; upper half 0.
    bf16x8 A1[6];
#pragma unroll
    for (int hg = 0; hg < 6; ++hg) {
        bf16x8 a = (bf16x8){0,0,0,0,0,0,0,0};
#pragma unroll
        for (int i = 0; i < 4; ++i)
            a[i] = f2bf(w1b[(4*g + i) * 96 + hg*16 + ln]);
        A1[hg] = a;
    }
    // A2[kk]: W2^T, row j = ln, slot (g,i) = h = 32kk + 16*(i>>2) + 4g + (i&3).
    bf16x8 A2[3];
#pragma unroll
    for (int kk = 0; kk < 3; ++kk) {
        bf16x8 a;
#pragma unroll
        for (int i = 0; i < 8; ++i) {
            const int h = 32*kk + 16*(i >> 2) + 4*g + (i & 3);
            a[i] = f2bf(w2b[h * 16 + ln]);
        }
        A2[kk] = a;
    }
    // bias1 as MFMA-C fragments: reg r <-> h = hgrp*16 + 4g + r
    f32x4 B1C[6];
#pragma unroll
    for (int hg = 0; hg < 6; ++hg)
        B1C[hg] = *reinterpret_cast<const f32x4*>(b1b + hg*16 + 4*g);
    const f32x4 b2f = *reinterpret_cast<const f32x4*>(b2b + 4*g);
    const f32x4 scf = *reinterpret_cast<const f32x4*>(scb + 4*g);

    // emb_h fragment pointer (lanes g<2: h = 4g+r < 8), th fixed
    const float* __restrict__ ehp = emb_h + ((size_t)b * 64 + th) * 8 + 4*g;

    const int row0 = obi * 256 + th * 4;
    const float* __restrict__ srow = sm  + (size_t)(row0 + g) * SM_N + ibi * 256 + ln * 4;
    float*       __restrict__ drow = out + (size_t)(row0 + g) * SM_N + ibi * 256 + ln * 4;

#pragma unroll 2
    for (int q = 0; q < 4; ++q) {
        const int tw = q * 16 + ln;
        const f32x4 x4 = *reinterpret_cast<const f32x4*>(srow + q * 64);

        // positional embedding for hgrp 0: g<2 -> emb_h[th], g>=2 -> emb_w[tw]
        const float* ep = (g < 2) ? ehp
                                  : (emb_w + ((size_t)b * 64 + tw) * 8 + 4*(g - 2));
        const f32x4 ef = *reinterpret_cast<const f32x4*>(ep);

        // GEMM1 B operand: tile sub-row g (4 bf16), upper K-half zero
        bf16x8 xb = (bf16x8){0,0,0,0,0,0,0,0};
#pragma unroll
        for (int i = 0; i < 4; ++i) xb[i] = f2bf(x4[i]);

        f32x4 D1[6];
        D1[0] = __builtin_amdgcn_mfma_f32_16x16x32_bf16(A1[0], xb, B1C[0] + ef, 0, 0, 0);
#pragma unroll
        for (int hg = 1; hg < 6; ++hg)
            D1[hg] = __builtin_amdgcn_mfma_f32_16x16x32_bf16(A1[hg], xb, B1C[hg], 0, 0, 0);

        // residual + bias2 as GEMM2's C (fp32, full precision on dominant term)
        f32x4 acc = b2f + x4 * scf;
#pragma unroll
        for (int kk = 0; kk < 3; ++kk) {
            bf16x8 p;
#pragma unroll
            for (int i = 0; i < 8; ++i)
                p[i] = f2bf(elu(D1[2*kk + (i >> 2)][i & 3]));
            acc = __builtin_amdgcn_mfma_f32_16x16x32_bf16(A2[kk], p, acc, 0, 0, 0);
        }

        *reinterpret_cast<f32x4*>(drow + q * 64) = acc;
    }
}

extern "C" void kernel_launch(void* const* d_in, const int* in_sizes, int n_in,
                              void* d_out, int out_size, void* d_ws, size_t ws_size,
                              hipStream_t stream) {
    const float* sm     = (const float*)d_in[0];
    const float* w1     = (const float*)d_in[1];
    const float* b1     = (const float*)d_in[2];
    const float* emb_h  = (const float*)d_in[3];
    const float* emb_w  = (const float*)d_in[4];
    const float* w2     = (const float*)d_in[5];
    const float* b2     = (const float*)d_in[6];
    const float* scales = (const float*)d_in[7];
    float* out = (float*)d_out;

    adapter_mfma<<<dim3(4096), dim3(256), 0, stream>>>(
        sm, w1, b1, emb_h, emb_w, w2, b2, scales, out);
}